// Round 6
// baseline (116.826 us; speedup 1.0000x reference)
//
#include <hip/hip_runtime.h>
#include <math.h>

#define HID 128
#define BQ 65536
#define NPIX_LR 524288
#define OW 512
#define NPIX_HR 2097152
#define OUT_OFF_DX 6291456
#define OUT_OFF_VAR 6291472

// ws layout (bytes)
#define WS_A2    0        // 32768 : w2^T A-frags f16 (64 tiles: T = t2*8+kt)
#define WS_A1    32768    // 4096  : w1^T (+b1) A-frags (8 tiles, split-exact)
#define WS_A3    36864    // 4096  : w3^T A-frags (8 k-tiles)
#define WS_VA1   40960    // 4096  : vw1^T (+vb1) A-frags, split-in-K (8 m-tiles)
#define WS_VA2H  45056    // 4096  : vw2^T hi A-frags (8 k-tiles)
#define WS_VA2L  49152    // 4096  : vw2^T lo A-frags (8 k-tiles)
#define WS_LR    53248    // 6291456 : low-res SoA f32

typedef __fp16   hf2   __attribute__((ext_vector_type(2)));
typedef _Float16 f16x4 __attribute__((ext_vector_type(4)));
typedef float    f32x4 __attribute__((ext_vector_type(4)));

static __device__ __host__ inline unsigned pack_f16pair(float a, float b) {
    hf2 h; h[0] = (__fp16)a; h[1] = (__fp16)b;
    return __builtin_bit_cast(unsigned, h);
}

// ---------------- Prep: pack weights into fragment layouts ----------------
__device__ inline float a1val(int k, int m, const float* w1, const float* b1) {
    if (k < 4) return w1[(k & 1) * HID + m];
    if (k < 6) { float v = w1[(k & 1) * HID + m]; return v - (float)(__fp16)v; }
    if (k == 8) return b1[m];
    if (k == 9) { float v = b1[m]; return v - (float)(__fp16)v; }
    return 0.f;
}

__device__ inline float va1val(int g, int j, int m, const float* vw1, const float* vb1) {
    // K slots: g0: vw1_hi rows 0..2 + vb1_hi; g1: vw1_hi (pairs o_lo) + 0;
    //          g2: vw1_lo (pairs o_hi) + vb1_lo; g3: 0
    if (g >= 3) return 0.f;
    if (j < 3) {
        float v = vw1[j * HID + m];
        if (g == 2) return v - (float)(__fp16)v;
        return v;   // cast to f16 in pack -> hi
    }
    if (g == 0) return vb1[m];
    if (g == 2) { float v = vb1[m]; return v - (float)(__fp16)v; }
    return 0.f;
}

__global__ void inr_prep(const float* __restrict__ w1, const float* __restrict__ b1,
                         const float* __restrict__ w2, const float* __restrict__ w3,
                         const float* __restrict__ vw1, const float* __restrict__ vb1,
                         const float* __restrict__ vw2, char* ws)
{
    int tid = blockIdx.x * 256 + threadIdx.x;
    if (tid < 8192) {
        // w2^T A-frags: tile T=t2*8+kt: A[m=16t2+li][k=16kt+g*4+j] = w2[k][m]
        int d = tid & 1, l = (tid >> 1) & 63, T = tid >> 7;
        int g = l >> 4, li = l & 15, t2 = T >> 3, kt = T & 7;
        int k = 16 * kt + g * 4 + 2 * d, col = 16 * t2 + li;
        unsigned u = pack_f16pair(w2[k * HID + col], w2[(k + 1) * HID + col]);
        ((unsigned*)(ws + WS_A2))[((T >> 1) * 64 + l) * 4 + (T & 1) * 2 + d] = u;
    } else if (tid < 9216) {
        int q = tid - 8192;
        int d = q & 1, l = (q >> 1) & 63, t = q >> 7;
        int g = l >> 4, li = l & 15, m = 16 * t + li;
        int k0 = g * 4 + 2 * d;
        unsigned u = pack_f16pair(a1val(k0, m, w1, b1), a1val(k0 + 1, m, w1, b1));
        ((unsigned*)(ws + WS_A1))[((t >> 1) * 64 + l) * 4 + (t & 1) * 2 + d] = u;
    } else if (tid < 10240) {
        int q = tid - 9216;
        int d = q & 1, l = (q >> 1) & 63, kt = q >> 7;
        int g = l >> 4, li = l & 15;
        int c0 = 16 * kt + g * 4 + 2 * d;
        float v0 = (li < 3) ? w3[c0 * 3 + li] : 0.f;
        float v1 = (li < 3) ? w3[(c0 + 1) * 3 + li] : 0.f;
        ((unsigned*)(ws + WS_A3))[((kt >> 1) * 64 + l) * 4 + (kt & 1) * 2 + d] = pack_f16pair(v0, v1);
    } else if (tid < 11264) {
        int q = tid - 10240;
        int d = q & 1, l = (q >> 1) & 63, t = q >> 7;
        int g = l >> 4, li = l & 15, m = 16 * t + li;
        unsigned u = pack_f16pair(va1val(g, 2 * d, m, vw1, vb1),
                                  va1val(g, 2 * d + 1, m, vw1, vb1));
        ((unsigned*)(ws + WS_VA1))[(t * 64 + l) * 2 + d] = u;
    } else if (tid < 12288) {
        int q = tid - 11264;
        int d = q & 1, l = (q >> 1) & 63, kt = q >> 7;
        int g = l >> 4, li = l & 15;
        int k0 = 16 * kt + g * 4 + 2 * d;
        float v0 = (li < 3) ? vw2[k0 * 3 + li] : 0.f;
        float v1 = (li < 3) ? vw2[(k0 + 1) * 3 + li] : 0.f;
        ((unsigned*)(ws + WS_VA2H))[(kt * 64 + l) * 2 + d] = pack_f16pair(v0, v1);
    } else if (tid < 13312) {
        int q = tid - 12288;
        int d = q & 1, l = (q >> 1) & 63, kt = q >> 7;
        int g = l >> 4, li = l & 15;
        int k0 = 16 * kt + g * 4 + 2 * d;
        float v0 = 0.f, v1 = 0.f;
        if (li < 3) {
            float a = vw2[k0 * 3 + li];       v0 = a - (float)(__fp16)a;
            float b = vw2[(k0 + 1) * 3 + li]; v1 = b - (float)(__fp16)b;
        }
        ((unsigned*)(ws + WS_VA2L))[(kt * 64 + l) * 2 + d] = pack_f16pair(v0, v1);
    }
}

// ---------------- Kernel A: all-MFMA MLP, one wave owns 16 px x 128 cols ----------------
__global__ __launch_bounds__(256, 2) void inr_mlp_mfma(
    const float* __restrict__ x, const int* __restrict__ sidx,
    const float* __restrict__ shv, const float* __restrict__ rot,
    const float* __restrict__ cw, const float* __restrict__ cb,
    const float* __restrict__ b2g, const float* __restrict__ b3g,
    const char* __restrict__ ws, float* __restrict__ lr)
{
    int tid = threadIdx.x, l = tid & 63, wv = tid >> 6;
    int li = l & 15, g = l >> 4;

    f16x4 A2[64], A1[8], A3[8];
    const uint4* p2 = (const uint4*)(ws + WS_A2);
    #pragma unroll
    for (int i = 0; i < 32; i++) {
        uint4 u = p2[i * 64 + l];
        uint2 a = {u.x, u.y}, b = {u.z, u.w};
        A2[2*i]   = __builtin_bit_cast(f16x4, a);
        A2[2*i+1] = __builtin_bit_cast(f16x4, b);
    }
    const uint4* p1 = (const uint4*)(ws + WS_A1);
    #pragma unroll
    for (int i = 0; i < 4; i++) {
        uint4 u = p1[i * 64 + l];
        uint2 a = {u.x, u.y}, b = {u.z, u.w};
        A1[2*i]   = __builtin_bit_cast(f16x4, a);
        A1[2*i+1] = __builtin_bit_cast(f16x4, b);
    }
    const uint4* p3 = (const uint4*)(ws + WS_A3);
    #pragma unroll
    for (int i = 0; i < 4; i++) {
        uint4 u = p3[i * 64 + l];
        uint2 a = {u.x, u.y}, b = {u.z, u.w};
        A3[2*i]   = __builtin_bit_cast(f16x4, a);
        A3[2*i+1] = __builtin_bit_cast(f16x4, b);
    }

    int base = blockIdx.x * 1024;
    int img = base >> 16;
    int si = sidx[img];
    float ang = rot[si], sn, cs;
    sincosf(ang, &sn, &cs);
    float shx = shv[2*si], shy = shv[2*si+1];
    bool aff = (si != 0);
    float cw0 = cw[si*3+0], cw1 = cw[si*3+1], cw2 = cw[si*3+2];
    float cb0 = cb[si*3+0], cb1 = cb[si*3+1], cb2 = cb[si*3+2];
    float b30 = b3g[0], b31 = b3g[1], b32 = b3g[2];
    const unsigned ONES = 0x3C003C00u;  // (1.0h, 1.0h)

    #pragma unroll 1
    for (int it = 0; it < 16; ++it) {
        int p0 = base + it * 64 + wv * 16;
        float2 xv = ((const float2*)x)[p0 + li];
        float cx = fmaf(cs, xv.x, fmaf(-sn, xv.y, shx));
        float cy = fmaf(sn, xv.x, fmaf(cs, xv.y, shy));
        hf2 ph = __builtin_amdgcn_cvt_pkrtz(cx, cy);
        float hx = (float)ph[0], hy = (float)ph[1];
        hf2 pl = __builtin_amdgcn_cvt_pkrtz(cx - hx, cy - hy);
        unsigned d0 = (g < 2) ? __builtin_bit_cast(unsigned, ph) : ((g == 2) ? ONES : 0u);
        unsigned d1 = (g == 0) ? __builtin_bit_cast(unsigned, pl) : 0u;
        uint2 b1u = {d0, d1};
        f16x4 B1 = __builtin_bit_cast(f16x4, b1u);

        f16x4 B2[8];
        #pragma unroll
        for (int t = 0; t < 8; t++) {
            f32x4 h = __builtin_amdgcn_mfma_f32_16x16x16f16(A1[t], B1, (f32x4){0.f,0.f,0.f,0.f}, 0, 0, 0);
            hf2 c01 = __builtin_amdgcn_cvt_pkrtz(fmaxf(h[0], 0.f), fmaxf(h[1], 0.f));
            hf2 c23 = __builtin_amdgcn_cvt_pkrtz(fmaxf(h[2], 0.f), fmaxf(h[3], 0.f));
            uint2 uu = {__builtin_bit_cast(unsigned, c01), __builtin_bit_cast(unsigned, c23)};
            B2[t] = __builtin_bit_cast(f16x4, uu);
        }

        f16x4 B3[8];
        #pragma unroll
        for (int t2 = 0; t2 < 8; t2++) {
            f32x4 c = *(const f32x4*)(b2g + 16 * t2 + g * 4);
            #pragma unroll
            for (int kt = 0; kt < 8; kt++)
                c = __builtin_amdgcn_mfma_f32_16x16x16f16(A2[t2 * 8 + kt], B2[kt], c, 0, 0, 0);
            hf2 c01 = __builtin_amdgcn_cvt_pkrtz(fmaxf(c[0], 0.f), fmaxf(c[1], 0.f));
            hf2 c23 = __builtin_amdgcn_cvt_pkrtz(fmaxf(c[2], 0.f), fmaxf(c[3], 0.f));
            uint2 uu = {__builtin_bit_cast(unsigned, c01), __builtin_bit_cast(unsigned, c23)};
            B3[t2] = __builtin_bit_cast(f16x4, uu);
        }

        f32x4 acc3a = {0.f,0.f,0.f,0.f}, acc3b = {0.f,0.f,0.f,0.f};
        #pragma unroll
        for (int k3 = 0; k3 < 8; k3 += 2) {
            acc3a = __builtin_amdgcn_mfma_f32_16x16x16f16(A3[k3],     B3[k3],     acc3a, 0, 0, 0);
            acc3b = __builtin_amdgcn_mfma_f32_16x16x16f16(A3[k3 + 1], B3[k3 + 1], acc3b, 0, 0, 0);
        }

        if (g == 0) {
            float v0 = acc3a[0] + acc3b[0] + b30;
            float v1 = acc3a[1] + acc3b[1] + b31;
            float v2 = acc3a[2] + acc3b[2] + b32;
            if (aff) {
                v0 = fmaf(v0, cw0, cb0);
                v1 = fmaf(v1, cw1, cb1);
                v2 = fmaf(v2, cw2, cb2);
            }
            lr[p0 + li] = v0;
            lr[NPIX_LR + p0 + li] = v1;
            lr[2 * NPIX_LR + p0 + li] = v2;
        }
    }
}

// ---------------- Kernel B: bilinear + MFMA variance MLP (16 px per wave-iter) ----------------
__global__ __launch_bounds__(256, 3) void inr_upsample_var(
    const float* __restrict__ lr, const int* __restrict__ sidx,
    const float* __restrict__ shv, const float* __restrict__ vb2g,
    const char* __restrict__ ws, float* __restrict__ out)
{
    int tid = threadIdx.x, l = tid & 63, wv = tid >> 6;
    int li = l & 15, g = l >> 4;

    f16x4 A1v[8], A2h[8], A2l[8];
    const uint2* q1 = (const uint2*)(ws + WS_VA1);
    const uint2* qh = (const uint2*)(ws + WS_VA2H);
    const uint2* ql = (const uint2*)(ws + WS_VA2L);
    #pragma unroll
    for (int t = 0; t < 8; t++) {
        A1v[t] = __builtin_bit_cast(f16x4, q1[t * 64 + l]);
        A2h[t] = __builtin_bit_cast(f16x4, qh[t * 64 + l]);
        A2l[t] = __builtin_bit_cast(f16x4, ql[t * 64 + l]);
    }
    float vb20 = vb2g[0], vb21 = vb2g[1], vb22 = vb2g[2];

    int group0 = (blockIdx.x * 4 + wv) * 16;   // 2048 blocks -> groups 0..131071
    #pragma unroll 1
    for (int it = 0; it < 16; ++it) {
        int grp = group0 + it;
        int px = grp * 16 + li;
        int b = px >> 18, r = px & 262143;
        int oy = r >> 9, ox = r & 511;

        int my = oy >> 1; int y0, y1; float wy0, wy1;
        if (oy & 1) { y0 = my; y1 = my < 255 ? my + 1 : 255; wy0 = 0.75f; wy1 = 0.25f; }
        else        { y0 = my > 0 ? my - 1 : 0; y1 = my;     wy0 = 0.25f; wy1 = 0.75f; }
        int mx = ox >> 1; int x0, x1; float wx0, wx1;
        if (ox & 1) { x0 = mx; x1 = mx < 255 ? mx + 1 : 255; wx0 = 0.75f; wx1 = 0.25f; }
        else        { x0 = mx > 0 ? mx - 1 : 0; x1 = mx;     wx0 = 0.25f; wx1 = 0.75f; }

        int base = b << 16;
        int i00 = base + y0 * 256 + x0, i01 = base + y0 * 256 + x1;
        int i10 = base + y1 * 256 + x0, i11 = base + y1 * 256 + x1;

        const float* L0 = lr;
        const float* L1 = lr + NPIX_LR;
        const float* L2 = lr + 2 * NPIX_LR;
        float o0 = wy0 * (wx0 * L0[i00] + wx1 * L0[i01]) + wy1 * (wx0 * L0[i10] + wx1 * L0[i11]);
        float o1 = wy0 * (wx0 * L1[i00] + wx1 * L1[i01]) + wy1 * (wx0 * L1[i10] + wx1 * L1[i11]);
        float o2 = wy0 * (wx0 * L2[i00] + wx1 * L2[i01]) + wy1 * (wx0 * L2[i10] + wx1 * L2[i11]);

        if (g == 1) {
            float* dst = out + (size_t)px * 3;
            dst[0] = o0; dst[1] = o1; dst[2] = o2;
        }

        // B1 frag: g0/g2: (o0h,o1h,o2h,1); g1: (o0l,o1l,o2l,0); g3: 0
        hf2 h01 = __builtin_amdgcn_cvt_pkrtz(o0, o1);
        hf2 h21 = __builtin_amdgcn_cvt_pkrtz(o2, 1.0f);
        hf2 l01 = __builtin_amdgcn_cvt_pkrtz(o0 - (float)h01[0], o1 - (float)h01[1]);
        hf2 l20 = __builtin_amdgcn_cvt_pkrtz(o2 - (float)h21[0], 0.0f);
        unsigned d0 = (g == 3) ? 0u : ((g == 1) ? __builtin_bit_cast(unsigned, l01)
                                                : __builtin_bit_cast(unsigned, h01));
        unsigned d1 = (g == 3) ? 0u : ((g == 1) ? __builtin_bit_cast(unsigned, l20)
                                                : __builtin_bit_cast(unsigned, h21));
        uint2 b1u = {d0, d1};
        f16x4 B1 = __builtin_bit_cast(f16x4, b1u);

        // v1: 8 MFMAs (split folded into K), relu + hi/lo pack
        f16x4 Bh[8], Bl[8];
        #pragma unroll
        for (int t = 0; t < 8; t++) {
            f32x4 vh = __builtin_amdgcn_mfma_f32_16x16x16f16(A1v[t], B1, (f32x4){0.f,0.f,0.f,0.f}, 0, 0, 0);
            float r0 = fmaxf(vh[0], 0.f), r1 = fmaxf(vh[1], 0.f);
            float r2 = fmaxf(vh[2], 0.f), r3 = fmaxf(vh[3], 0.f);
            hf2 c01 = __builtin_amdgcn_cvt_pkrtz(r0, r1);
            hf2 c23 = __builtin_amdgcn_cvt_pkrtz(r2, r3);
            hf2 e01 = __builtin_amdgcn_cvt_pkrtz(r0 - (float)c01[0], r1 - (float)c01[1]);
            hf2 e23 = __builtin_amdgcn_cvt_pkrtz(r2 - (float)c23[0], r3 - (float)c23[1]);
            uint2 uh = {__builtin_bit_cast(unsigned, c01), __builtin_bit_cast(unsigned, c23)};
            uint2 ul = {__builtin_bit_cast(unsigned, e01), __builtin_bit_cast(unsigned, e23)};
            Bh[t] = __builtin_bit_cast(f16x4, uh);
            Bl[t] = __builtin_bit_cast(f16x4, ul);
        }

        // v2: 3-pass split (A2h*Bh + A2h*Bl + A2l*Bh)
        f32x4 aA = {0.f,0.f,0.f,0.f}, aB = {0.f,0.f,0.f,0.f}, aC = {0.f,0.f,0.f,0.f};
        #pragma unroll
        for (int kt = 0; kt < 8; kt++) {
            aA = __builtin_amdgcn_mfma_f32_16x16x16f16(A2h[kt], Bh[kt], aA, 0, 0, 0);
            aB = __builtin_amdgcn_mfma_f32_16x16x16f16(A2h[kt], Bl[kt], aB, 0, 0, 0);
            aC = __builtin_amdgcn_mfma_f32_16x16x16f16(A2l[kt], Bh[kt], aC, 0, 0, 0);
        }

        if (g == 0) {   // rows 0..2 = channels, col = px = li
            float a0 = aA[0] + aB[0] + aC[0] + vb20;
            float a1 = aA[1] + aB[1] + aC[1] + vb21;
            float a2 = aA[2] + aB[2] + aC[2] + vb22;
            float* var = out + OUT_OFF_VAR + (size_t)px * 3;
            var[0] = expf(a0); var[1] = expf(a1); var[2] = expf(a2);
        }
    }

    if (blockIdx.x == 0 && tid < 16) {
        out[OUT_OFF_DX + tid] = shv[2 * sidx[tid & 7] + (tid >> 3)];
    }
}

extern "C" void kernel_launch(void* const* d_in, const int* in_sizes, int n_in,
                              void* d_out, int out_size, void* d_ws, size_t ws_size,
                              hipStream_t stream)
{
    const float* x    = (const float*)d_in[0];
    const int*   sidx = (const int*)d_in[1];
    const float* shv  = (const float*)d_in[3];
    const float* rot  = (const float*)d_in[4];
    const float* cwp  = (const float*)d_in[5];
    const float* cbp  = (const float*)d_in[6];
    const float* w1   = (const float*)d_in[7];
    const float* b1   = (const float*)d_in[8];
    const float* w2   = (const float*)d_in[9];
    const float* b2   = (const float*)d_in[10];
    const float* w3   = (const float*)d_in[11];
    const float* b3   = (const float*)d_in[12];
    const float* vw1  = (const float*)d_in[13];
    const float* vb1  = (const float*)d_in[14];
    const float* vw2  = (const float*)d_in[15];
    const float* vb2  = (const float*)d_in[16];

    char* ws = (char*)d_ws;
    float* lr = (float*)(ws + WS_LR);

    inr_prep<<<52, 256, 0, stream>>>(w1, b1, w2, w3, vw1, vb1, vw2, ws);
    inr_mlp_mfma<<<512, 256, 0, stream>>>(x, sidx, shv, rot, cwp, cbp, b2, b3, ws, lr);
    inr_upsample_var<<<2048, 256, 0, stream>>>(lr, sidx, shv, vb2, ws, (float*)d_out);
}

// Round 7
// 81.196 us; speedup vs baseline: 1.4388x; 1.4388x over previous
//
#include <hip/hip_runtime.h>
#include <math.h>

#define HID 128
#define BQ 65536
#define NPIX_LR 524288
#define OW 512
#define NPIX_HR 2097152
#define OUT_OFF_DX 6291456
#define OUT_OFF_VAR 6291472

// ws layout (bytes)
#define WS_A2    0        // 32768 : w2^T A-frags f16 (64 tiles: T = t2*8+kt)
#define WS_A1    32768    // 4096  : w1^T (+b1) A-frags (8 tiles, split-exact)
#define WS_A3    36864    // 4096  : w3^T A-frags (8 k-tiles)
#define WS_VA1   40960    // 4096  : vw1^T (+vb1) A-frags, split-in-K (8 m-tiles)
#define WS_VA2H  45056    // 4096  : vw2^T hi A-frags (8 k-tiles)
#define WS_VA2L  49152    // 4096  : vw2^T lo A-frags (8 k-tiles)
#define WS_LR    53248    // 6291456 : low-res SoA f32

typedef __fp16   hf2   __attribute__((ext_vector_type(2)));
typedef _Float16 f16x4 __attribute__((ext_vector_type(4)));
typedef float    f32x4 __attribute__((ext_vector_type(4)));

static __device__ __host__ inline unsigned pack_f16pair(float a, float b) {
    hf2 h; h[0] = (__fp16)a; h[1] = (__fp16)b;
    return __builtin_bit_cast(unsigned, h);
}

// ---------------- Prep: pack weights into fragment layouts ----------------
__device__ inline float a1val(int k, int m, const float* w1, const float* b1) {
    if (k < 4) return w1[(k & 1) * HID + m];
    if (k < 6) { float v = w1[(k & 1) * HID + m]; return v - (float)(__fp16)v; }
    if (k == 8) return b1[m];
    if (k == 9) { float v = b1[m]; return v - (float)(__fp16)v; }
    return 0.f;
}

__device__ inline float va1val(int g, int j, int m, const float* vw1, const float* vb1) {
    // K slots: g0: vw1_hi rows 0..2 + vb1_hi; g1: vw1_hi (pairs o_lo) + 0;
    //          g2: vw1_lo (pairs o_hi) + vb1_lo; g3: 0
    if (g >= 3) return 0.f;
    if (j < 3) {
        float v = vw1[j * HID + m];
        if (g == 2) return v - (float)(__fp16)v;
        return v;   // cast to f16 in pack -> hi
    }
    if (g == 0) return vb1[m];
    if (g == 2) { float v = vb1[m]; return v - (float)(__fp16)v; }
    return 0.f;
}

__global__ void inr_prep(const float* __restrict__ w1, const float* __restrict__ b1,
                         const float* __restrict__ w2, const float* __restrict__ w3,
                         const float* __restrict__ vw1, const float* __restrict__ vb1,
                         const float* __restrict__ vw2, char* ws)
{
    int tid = blockIdx.x * 256 + threadIdx.x;
    if (tid < 8192) {
        // w2^T A-frags: tile T=t2*8+kt: A[m=16t2+li][k=16kt+g*4+j] = w2[k][m]
        int d = tid & 1, l = (tid >> 1) & 63, T = tid >> 7;
        int g = l >> 4, li = l & 15, t2 = T >> 3, kt = T & 7;
        int k = 16 * kt + g * 4 + 2 * d, col = 16 * t2 + li;
        unsigned u = pack_f16pair(w2[k * HID + col], w2[(k + 1) * HID + col]);
        ((unsigned*)(ws + WS_A2))[((T >> 1) * 64 + l) * 4 + (T & 1) * 2 + d] = u;
    } else if (tid < 9216) {
        int q = tid - 8192;
        int d = q & 1, l = (q >> 1) & 63, t = q >> 7;
        int g = l >> 4, li = l & 15, m = 16 * t + li;
        int k0 = g * 4 + 2 * d;
        unsigned u = pack_f16pair(a1val(k0, m, w1, b1), a1val(k0 + 1, m, w1, b1));
        ((unsigned*)(ws + WS_A1))[((t >> 1) * 64 + l) * 4 + (t & 1) * 2 + d] = u;
    } else if (tid < 10240) {
        int q = tid - 9216;
        int d = q & 1, l = (q >> 1) & 63, kt = q >> 7;
        int g = l >> 4, li = l & 15;
        int c0 = 16 * kt + g * 4 + 2 * d;
        float v0 = (li < 3) ? w3[c0 * 3 + li] : 0.f;
        float v1 = (li < 3) ? w3[(c0 + 1) * 3 + li] : 0.f;
        ((unsigned*)(ws + WS_A3))[((kt >> 1) * 64 + l) * 4 + (kt & 1) * 2 + d] = pack_f16pair(v0, v1);
    } else if (tid < 11264) {
        int q = tid - 10240;
        int d = q & 1, l = (q >> 1) & 63, t = q >> 7;
        int g = l >> 4, li = l & 15, m = 16 * t + li;
        unsigned u = pack_f16pair(va1val(g, 2 * d, m, vw1, vb1),
                                  va1val(g, 2 * d + 1, m, vw1, vb1));
        ((unsigned*)(ws + WS_VA1))[(t * 64 + l) * 2 + d] = u;
    } else if (tid < 12288) {
        int q = tid - 11264;
        int d = q & 1, l = (q >> 1) & 63, kt = q >> 7;
        int g = l >> 4, li = l & 15;
        int k0 = 16 * kt + g * 4 + 2 * d;
        float v0 = (li < 3) ? vw2[k0 * 3 + li] : 0.f;
        float v1 = (li < 3) ? vw2[(k0 + 1) * 3 + li] : 0.f;
        ((unsigned*)(ws + WS_VA2H))[(kt * 64 + l) * 2 + d] = pack_f16pair(v0, v1);
    }
}

// ---------------- Kernel A: all-MFMA MLP, one wave owns 16 px x 128 cols ----------------
__global__ __launch_bounds__(256, 2) void inr_mlp_mfma(
    const float* __restrict__ x, const int* __restrict__ sidx,
    const float* __restrict__ shv, const float* __restrict__ rot,
    const float* __restrict__ cw, const float* __restrict__ cb,
    const float* __restrict__ b2g, const float* __restrict__ b3g,
    const char* __restrict__ ws, float* __restrict__ lr)
{
    int tid = threadIdx.x, l = tid & 63, wv = tid >> 6;
    int li = l & 15, g = l >> 4;

    f16x4 A2[64], A1[8], A3[8];
    const uint4* p2 = (const uint4*)(ws + WS_A2);
    #pragma unroll
    for (int i = 0; i < 32; i++) {
        uint4 u = p2[i * 64 + l];
        uint2 a = {u.x, u.y}, b = {u.z, u.w};
        A2[2*i]   = __builtin_bit_cast(f16x4, a);
        A2[2*i+1] = __builtin_bit_cast(f16x4, b);
    }
    const uint4* p1 = (const uint4*)(ws + WS_A1);
    #pragma unroll
    for (int i = 0; i < 4; i++) {
        uint4 u = p1[i * 64 + l];
        uint2 a = {u.x, u.y}, b = {u.z, u.w};
        A1[2*i]   = __builtin_bit_cast(f16x4, a);
        A1[2*i+1] = __builtin_bit_cast(f16x4, b);
    }
    const uint4* p3 = (const uint4*)(ws + WS_A3);
    #pragma unroll
    for (int i = 0; i < 4; i++) {
        uint4 u = p3[i * 64 + l];
        uint2 a = {u.x, u.y}, b = {u.z, u.w};
        A3[2*i]   = __builtin_bit_cast(f16x4, a);
        A3[2*i+1] = __builtin_bit_cast(f16x4, b);
    }

    int base = blockIdx.x * 1024;
    int img = base >> 16;
    int si = sidx[img];
    float ang = rot[si], sn, cs;
    sincosf(ang, &sn, &cs);
    float shx = shv[2*si], shy = shv[2*si+1];
    bool aff = (si != 0);
    float cw0 = cw[si*3+0], cw1 = cw[si*3+1], cw2 = cw[si*3+2];
    float cb0 = cb[si*3+0], cb1 = cb[si*3+1], cb2 = cb[si*3+2];
    float b30 = b3g[0], b31 = b3g[1], b32 = b3g[2];
    const unsigned ONES = 0x3C003C00u;  // (1.0h, 1.0h)

    #pragma unroll 1
    for (int it = 0; it < 16; ++it) {
        int p0 = base + it * 64 + wv * 16;
        float2 xv = ((const float2*)x)[p0 + li];
        float cx = fmaf(cs, xv.x, fmaf(-sn, xv.y, shx));
        float cy = fmaf(sn, xv.x, fmaf(cs, xv.y, shy));
        hf2 ph = __builtin_amdgcn_cvt_pkrtz(cx, cy);
        float hx = (float)ph[0], hy = (float)ph[1];
        hf2 pl = __builtin_amdgcn_cvt_pkrtz(cx - hx, cy - hy);
        unsigned d0 = (g < 2) ? __builtin_bit_cast(unsigned, ph) : ((g == 2) ? ONES : 0u);
        unsigned d1 = (g == 0) ? __builtin_bit_cast(unsigned, pl) : 0u;
        uint2 b1u = {d0, d1};
        f16x4 B1 = __builtin_bit_cast(f16x4, b1u);

        f16x4 B2[8];
        #pragma unroll
        for (int t = 0; t < 8; t++) {
            f32x4 h = __builtin_amdgcn_mfma_f32_16x16x16f16(A1[t], B1, (f32x4){0.f,0.f,0.f,0.f}, 0, 0, 0);
            hf2 c01 = __builtin_amdgcn_cvt_pkrtz(fmaxf(h[0], 0.f), fmaxf(h[1], 0.f));
            hf2 c23 = __builtin_amdgcn_cvt_pkrtz(fmaxf(h[2], 0.f), fmaxf(h[3], 0.f));
            uint2 uu = {__builtin_bit_cast(unsigned, c01), __builtin_bit_cast(unsigned, c23)};
            B2[t] = __builtin_bit_cast(f16x4, uu);
        }

        f16x4 B3[8];
        #pragma unroll
        for (int t2 = 0; t2 < 8; t2++) {
            f32x4 c = *(const f32x4*)(b2g + 16 * t2 + g * 4);
            #pragma unroll
            for (int kt = 0; kt < 8; kt++)
                c = __builtin_amdgcn_mfma_f32_16x16x16f16(A2[t2 * 8 + kt], B2[kt], c, 0, 0, 0);
            hf2 c01 = __builtin_amdgcn_cvt_pkrtz(fmaxf(c[0], 0.f), fmaxf(c[1], 0.f));
            hf2 c23 = __builtin_amdgcn_cvt_pkrtz(fmaxf(c[2], 0.f), fmaxf(c[3], 0.f));
            uint2 uu = {__builtin_bit_cast(unsigned, c01), __builtin_bit_cast(unsigned, c23)};
            B3[t2] = __builtin_bit_cast(f16x4, uu);
        }

        f32x4 acc3a = {0.f,0.f,0.f,0.f}, acc3b = {0.f,0.f,0.f,0.f};
        #pragma unroll
        for (int k3 = 0; k3 < 8; k3 += 2) {
            acc3a = __builtin_amdgcn_mfma_f32_16x16x16f16(A3[k3],     B3[k3],     acc3a, 0, 0, 0);
            acc3b = __builtin_amdgcn_mfma_f32_16x16x16f16(A3[k3 + 1], B3[k3 + 1], acc3b, 0, 0, 0);
        }

        if (g == 0) {
            float v0 = acc3a[0] + acc3b[0] + b30;
            float v1 = acc3a[1] + acc3b[1] + b31;
            float v2 = acc3a[2] + acc3b[2] + b32;
            if (aff) {
                v0 = fmaf(v0, cw0, cb0);
                v1 = fmaf(v1, cw1, cb1);
                v2 = fmaf(v2, cw2, cb2);
            }
            lr[p0 + li] = v0;
            lr[NPIX_LR + p0 + li] = v1;
            lr[2 * NPIX_LR + p0 + li] = v2;
        }
    }
}

// ---------------- Kernel B: 64 px/wave-iter bilinear + MFMA variance MLP ----------------
// Each lane computes bilinear for its OWN pixel; __shfl redistributes the 3
// channel values to fragment lanes per 16-px sub-group. v2 single hi-pass.
#define B_ITERS 8
__global__ __launch_bounds__(256, 4) void inr_upsample_var(
    const float* __restrict__ lr, const int* __restrict__ sidx,
    const float* __restrict__ shv, const float* __restrict__ vb2g,
    const char* __restrict__ ws, float* __restrict__ out)
{
    int tid = threadIdx.x, l = tid & 63, wv = tid >> 6;
    int li = l & 15, g = l >> 4;

    f16x4 A1v[8], A2h[8];
    const uint2* q1 = (const uint2*)(ws + WS_VA1);
    const uint2* qh = (const uint2*)(ws + WS_VA2H);
    #pragma unroll
    for (int t = 0; t < 8; t++) {
        A1v[t] = __builtin_bit_cast(f16x4, q1[t * 64 + l]);
        A2h[t] = __builtin_bit_cast(f16x4, qh[t * 64 + l]);
    }
    float vb20 = vb2g[0], vb21 = vb2g[1], vb22 = vb2g[2];

    int wbase = (blockIdx.x * 4 + wv) * (64 * B_ITERS);
    #pragma unroll 1
    for (int it = 0; it < B_ITERS; ++it) {
        int pxb = wbase + it * 64;
        int px = pxb + l;
        int b = px >> 18, r = px & 262143;
        int oy = r >> 9, ox = r & 511;

        int my = oy >> 1; int y0, y1; float wy0, wy1;
        if (oy & 1) { y0 = my; y1 = my < 255 ? my + 1 : 255; wy0 = 0.75f; wy1 = 0.25f; }
        else        { y0 = my > 0 ? my - 1 : 0; y1 = my;     wy0 = 0.25f; wy1 = 0.75f; }
        int mx = ox >> 1; int x0, x1; float wx0, wx1;
        if (ox & 1) { x0 = mx; x1 = mx < 255 ? mx + 1 : 255; wx0 = 0.75f; wx1 = 0.25f; }
        else        { x0 = mx > 0 ? mx - 1 : 0; x1 = mx;     wx0 = 0.25f; wx1 = 0.75f; }

        int base = b << 16;
        int i00 = base + y0 * 256 + x0, i01 = base + y0 * 256 + x1;
        int i10 = base + y1 * 256 + x0, i11 = base + y1 * 256 + x1;

        const float* L0 = lr;
        const float* L1 = lr + NPIX_LR;
        const float* L2 = lr + 2 * NPIX_LR;
        float o0 = wy0 * (wx0 * L0[i00] + wx1 * L0[i01]) + wy1 * (wx0 * L0[i10] + wx1 * L0[i11]);
        float o1 = wy0 * (wx0 * L1[i00] + wx1 * L1[i01]) + wy1 * (wx0 * L1[i10] + wx1 * L1[i11]);
        float o2 = wy0 * (wx0 * L2[i00] + wx1 * L2[i01]) + wy1 * (wx0 * L2[i10] + wx1 * L2[i11]);

        {
            float* dst = out + (size_t)px * 3;
            dst[0] = o0; dst[1] = o1; dst[2] = o2;
        }

        #pragma unroll
        for (int j = 0; j < 4; j++) {
            int srcl = j * 16 + li;
            float p0 = __shfl(o0, srcl, 64);
            float p1 = __shfl(o1, srcl, 64);
            float p2 = __shfl(o2, srcl, 64);

            // B1: g0/g2: (p0h,p1h,p2h,1); g1: (p0l,p1l,p2l,0); g3: 0
            hf2 h01 = __builtin_amdgcn_cvt_pkrtz(p0, p1);
            hf2 h21 = __builtin_amdgcn_cvt_pkrtz(p2, 1.0f);
            hf2 l01 = __builtin_amdgcn_cvt_pkrtz(p0 - (float)h01[0], p1 - (float)h01[1]);
            hf2 l20 = __builtin_amdgcn_cvt_pkrtz(p2 - (float)h21[0], 0.0f);
            unsigned d0 = (g == 3) ? 0u : ((g == 1) ? __builtin_bit_cast(unsigned, l01)
                                                    : __builtin_bit_cast(unsigned, h01));
            unsigned d1 = (g == 3) ? 0u : ((g == 1) ? __builtin_bit_cast(unsigned, l20)
                                                    : __builtin_bit_cast(unsigned, h21));
            uint2 b1u = {d0, d1};
            f16x4 B1 = __builtin_bit_cast(f16x4, b1u);

            // v1: 8 MFMAs (split folded into K slots), relu + hi pack only
            f16x4 B2[8];
            #pragma unroll
            for (int t = 0; t < 8; t++) {
                f32x4 vh = __builtin_amdgcn_mfma_f32_16x16x16f16(A1v[t], B1, (f32x4){0.f,0.f,0.f,0.f}, 0, 0, 0);
                hf2 c01 = __builtin_amdgcn_cvt_pkrtz(fmaxf(vh[0], 0.f), fmaxf(vh[1], 0.f));
                hf2 c23 = __builtin_amdgcn_cvt_pkrtz(fmaxf(vh[2], 0.f), fmaxf(vh[3], 0.f));
                uint2 uu = {__builtin_bit_cast(unsigned, c01), __builtin_bit_cast(unsigned, c23)};
                B2[t] = __builtin_bit_cast(f16x4, uu);
            }

            // v2: single hi-pass, 8 MFMAs
            f32x4 acc = {0.f, 0.f, 0.f, 0.f};
            #pragma unroll
            for (int kt = 0; kt < 8; kt++)
                acc = __builtin_amdgcn_mfma_f32_16x16x16f16(A2h[kt], B2[kt], acc, 0, 0, 0);

            if (g == 0) {   // rows 0..2 = channels, col = px = li
                float* var = out + OUT_OFF_VAR + (size_t)(pxb + j * 16 + li) * 3;
                var[0] = __expf(acc[0] + vb20);
                var[1] = __expf(acc[1] + vb21);
                var[2] = __expf(acc[2] + vb22);
            }
        }
    }

    if (blockIdx.x == 0 && tid < 16) {
        out[OUT_OFF_DX + tid] = shv[2 * sidx[tid & 7] + (tid >> 3)];
    }
}

extern "C" void kernel_launch(void* const* d_in, const int* in_sizes, int n_in,
                              void* d_out, int out_size, void* d_ws, size_t ws_size,
                              hipStream_t stream)
{
    const float* x    = (const float*)d_in[0];
    const int*   sidx = (const int*)d_in[1];
    const float* shv  = (const float*)d_in[3];
    const float* rot  = (const float*)d_in[4];
    const float* cwp  = (const float*)d_in[5];
    const float* cbp  = (const float*)d_in[6];
    const float* w1   = (const float*)d_in[7];
    const float* b1   = (const float*)d_in[8];
    const float* w2   = (const float*)d_in[9];
    const float* b2   = (const float*)d_in[10];
    const float* w3   = (const float*)d_in[11];
    const float* b3   = (const float*)d_in[12];
    const float* vw1  = (const float*)d_in[13];
    const float* vb1  = (const float*)d_in[14];
    const float* vw2  = (const float*)d_in[15];
    const float* vb2  = (const float*)d_in[16];

    char* ws = (char*)d_ws;
    float* lr = (float*)(ws + WS_LR);

    inr_prep<<<48, 256, 0, stream>>>(w1, b1, w2, w3, vw1, vb1, vw2, ws);
    inr_mlp_mfma<<<512, 256, 0, stream>>>(x, sidx, shv, rot, cwp, cbp, b2, b3, ws, lr);
    inr_upsample_var<<<NPIX_HR / (256 * 64 * B_ITERS / 64), 256, 0, stream>>>(lr, sidx, shv, vb2, ws, (float*)d_out);
}

// Round 8
// 75.657 us; speedup vs baseline: 1.5442x; 1.0732x over previous
//
#include <hip/hip_runtime.h>
#include <math.h>

#define HID 128
#define BQ 65536
#define NPIX_LR 524288
#define OW 512
#define NPIX_HR 2097152
#define OUT_OFF_DX 6291456
#define OUT_OFF_VAR 6291472

// ws layout (bytes)
#define WS_A2    0        // 32768 : w2^T K32-frags (32 tiles: T = t2*4+kt), sigma-packed
#define WS_A1    32768    // 8192  : w1^T (+b1) K32-frags (8 m-tiles, split in k-slots)
#define WS_A3    40960    // 4096  : w3^T K32-frags (4 k-tiles), sigma-packed
#define WS_VA1   45056    // 8192  : vw1^T (+vb1) K32-frags (8 m-tiles, split in k-slots)
#define WS_VA2H  53248    // 4096  : vw2^T K32-frags (4 k-tiles), sigma-packed
#define WS_LR    57344    // 6291456 : low-res SoA f32

typedef __fp16   hf2   __attribute__((ext_vector_type(2)));
typedef _Float16 f16x8 __attribute__((ext_vector_type(8)));
typedef float    f32x4 __attribute__((ext_vector_type(4)));

static __device__ inline unsigned pack_f16pair(float a, float b) {
    hf2 h; h[0] = (__fp16)a; h[1] = (__fp16)b;
    return __builtin_bit_cast(unsigned, h);
}
static __device__ inline float f16lo(float v) { return v - (float)(__fp16)v; }

// ---------------- Prep ----------------
// sigma: k-slot for frag elem (kt, g, j) = (2kt + (j>=4))*16 + g*4 + (j&3)
__device__ inline int sigma(int kt, int g, int j) {
    return (2 * kt + (j >> 2)) * 16 + g * 4 + (j & 3);
}

__device__ inline float a1v32(int g, int j, int m, const float* w1, const float* b1) {
    if (g != 0) return 0.f;
    switch (j) {
    case 0: return w1[m];               // w_hi x  (x c_hi)
    case 1: return w1[HID + m];         // w_hi y
    case 2: return w1[m];               // w_hi x  (x c_lo)
    case 3: return w1[HID + m];
    case 4: return f16lo(w1[m]);        // w_lo x  (x c_hi)
    case 5: return f16lo(w1[HID + m]);
    case 6: return b1[m];               // b_hi (x 1)
    case 7: return f16lo(b1[m]);        // b_lo (x 1)
    }
    return 0.f;
}

__device__ inline float va1v32(int g, int j, int m, const float* vw1, const float* vb1) {
    if (g == 0) {
        if (j < 3) return vw1[j * HID + m];          // vw_hi (x p_hi)
        if (j < 6) return vw1[(j - 3) * HID + m];    // vw_hi (x p_lo)
        if (j == 6) return vb1[m];                   // vb_hi
        return f16lo(vb1[m]);                        // vb_lo
    }
    if (g == 1 && j < 3) return f16lo(vw1[j * HID + m]);  // vw_lo (x p_hi)
    return 0.f;
}

__global__ void inr_prep(const float* __restrict__ w1, const float* __restrict__ b1,
                         const float* __restrict__ w2, const float* __restrict__ w3,
                         const float* __restrict__ vw1, const float* __restrict__ vb1,
                         const float* __restrict__ vw2, char* ws)
{
    int tid = blockIdx.x * 256 + threadIdx.x;
    if (tid < 8192) {                      // A2: 32 tiles (t2*4+kt)
        int d = tid & 3, l = (tid >> 2) & 63, T = tid >> 8;
        int g = l >> 4, li = l & 15, t2 = T >> 2, kt = T & 3;
        int col = 16 * t2 + li;
        int s0 = sigma(kt, g, 2 * d), s1 = sigma(kt, g, 2 * d + 1);
        ((unsigned*)(ws + WS_A2))[tid] = pack_f16pair(w2[s0 * HID + col], w2[s1 * HID + col]);
    } else if (tid < 10240) {              // A1: 8 m-tiles
        int q = tid - 8192;
        int d = q & 3, l = (q >> 2) & 63, t = q >> 8;
        int g = l >> 4, li = l & 15, m = 16 * t + li;
        ((unsigned*)(ws + WS_A1))[q] = pack_f16pair(a1v32(g, 2 * d, m, w1, b1),
                                                    a1v32(g, 2 * d + 1, m, w1, b1));
    } else if (tid < 11264) {              // A3: 4 k-tiles
        int q = tid - 10240;
        int d = q & 3, l = (q >> 2) & 63, kt = q >> 8;
        int g = l >> 4, li = l & 15;
        int s0 = sigma(kt, g, 2 * d), s1 = sigma(kt, g, 2 * d + 1);
        float v0 = (li < 3) ? w3[s0 * 3 + li] : 0.f;
        float v1 = (li < 3) ? w3[s1 * 3 + li] : 0.f;
        ((unsigned*)(ws + WS_A3))[q] = pack_f16pair(v0, v1);
    } else if (tid < 13312) {              // VA1: 8 m-tiles
        int q = tid - 11264;
        int d = q & 3, l = (q >> 2) & 63, t = q >> 8;
        int g = l >> 4, li = l & 15, m = 16 * t + li;
        ((unsigned*)(ws + WS_VA1))[q] = pack_f16pair(va1v32(g, 2 * d, m, vw1, vb1),
                                                     va1v32(g, 2 * d + 1, m, vw1, vb1));
    } else if (tid < 14336) {              // VA2H: 4 k-tiles
        int q = tid - 13312;
        int d = q & 3, l = (q >> 2) & 63, kt = q >> 8;
        int g = l >> 4, li = l & 15;
        int s0 = sigma(kt, g, 2 * d), s1 = sigma(kt, g, 2 * d + 1);
        float v0 = (li < 3) ? vw2[s0 * 3 + li] : 0.f;
        float v1 = (li < 3) ? vw2[s1 * 3 + li] : 0.f;
        ((unsigned*)(ws + WS_VA2H))[q] = pack_f16pair(v0, v1);
    }
}

// ---------------- Kernel A: all-K32-MFMA MLP, one wave owns 16 px x 128 cols ----------------
__global__ __launch_bounds__(256, 2) void inr_mlp_mfma(
    const float* __restrict__ x, const int* __restrict__ sidx,
    const float* __restrict__ shv, const float* __restrict__ rot,
    const float* __restrict__ cw, const float* __restrict__ cb,
    const float* __restrict__ b2g, const float* __restrict__ b3g,
    const char* __restrict__ ws, float* __restrict__ lr)
{
    int tid = threadIdx.x, l = tid & 63, wv = tid >> 6;
    int li = l & 15, g = l >> 4;

    f16x8 A2[32], A1[8], A3[4];
    const uint4* p2 = (const uint4*)(ws + WS_A2);
    #pragma unroll
    for (int i = 0; i < 32; i++) A2[i] = __builtin_bit_cast(f16x8, p2[i * 64 + l]);
    const uint4* p1 = (const uint4*)(ws + WS_A1);
    #pragma unroll
    for (int i = 0; i < 8; i++) A1[i] = __builtin_bit_cast(f16x8, p1[i * 64 + l]);
    const uint4* p3 = (const uint4*)(ws + WS_A3);
    #pragma unroll
    for (int i = 0; i < 4; i++) A3[i] = __builtin_bit_cast(f16x8, p3[i * 64 + l]);

    int base = blockIdx.x * 1024;
    int img = base >> 16;
    int si = sidx[img];
    float ang = rot[si], sn, cs;
    sincosf(ang, &sn, &cs);
    float shx = shv[2*si], shy = shv[2*si+1];
    bool aff = (si != 0);
    float cw0 = cw[si*3+0], cw1 = cw[si*3+1], cw2 = cw[si*3+2];
    float cb0 = cb[si*3+0], cb1 = cb[si*3+1], cb2 = cb[si*3+2];
    float b30 = b3g[0], b31 = b3g[1], b32 = b3g[2];
    const unsigned ONES = 0x3C003C00u;  // (1.0h, 1.0h)

    #pragma unroll 1
    for (int it = 0; it < 16; ++it) {
        int p0 = base + it * 64 + wv * 16;
        float2 xv = ((const float2*)x)[p0 + li];
        float cx = fmaf(cs, xv.x, fmaf(-sn, xv.y, shx));
        float cy = fmaf(sn, xv.x, fmaf(cs, xv.y, shy));
        hf2 ph = __builtin_amdgcn_cvt_pkrtz(cx, cy);
        hf2 pl = __builtin_amdgcn_cvt_pkrtz(cx - (float)ph[0], cy - (float)ph[1]);
        unsigned uh = __builtin_bit_cast(unsigned, ph);
        unsigned ul = __builtin_bit_cast(unsigned, pl);
        // B1 (g0 k-slots): cxh,cyh,cxl,cyl,cxh,cyh,1,1 ; other groups 0
        uint4 b1u;
        b1u.x = (g == 0) ? uh : 0u;
        b1u.y = (g == 0) ? ul : 0u;
        b1u.z = (g == 0) ? uh : 0u;
        b1u.w = (g == 0) ? ONES : 0u;
        f16x8 B1 = __builtin_bit_cast(f16x8, b1u);

        // layer 1: 8 x K32 MFMA -> relu -> pack into uint2 per tile
        uint2 C1[8];
        #pragma unroll
        for (int t = 0; t < 8; t++) {
            f32x4 h = __builtin_amdgcn_mfma_f32_16x16x32_f16(A1[t], B1, (f32x4){0.f,0.f,0.f,0.f}, 0, 0, 0);
            C1[t].x = pack_f16pair(fmaxf(h[0], 0.f), fmaxf(h[1], 0.f));
            C1[t].y = pack_f16pair(fmaxf(h[2], 0.f), fmaxf(h[3], 0.f));
        }

        // layer 2: 8 m-tiles x 4 k-tiles, B frag = concat of two C1 tiles (sigma-packed A2)
        uint2 C2[8];
        #pragma unroll
        for (int t2 = 0; t2 < 8; t2++) {
            f32x4 c = *(const f32x4*)(b2g + 16 * t2 + g * 4);
            #pragma unroll
            for (int kt = 0; kt < 4; kt++) {
                uint4 bu = {C1[2*kt].x, C1[2*kt].y, C1[2*kt+1].x, C1[2*kt+1].y};
                c = __builtin_amdgcn_mfma_f32_16x16x32_f16(A2[t2 * 4 + kt],
                        __builtin_bit_cast(f16x8, bu), c, 0, 0, 0);
            }
            C2[t2].x = pack_f16pair(fmaxf(c[0], 0.f), fmaxf(c[1], 0.f));
            C2[t2].y = pack_f16pair(fmaxf(c[2], 0.f), fmaxf(c[3], 0.f));
        }

        // layer 3: 4 k-tiles into 2 chains
        f32x4 acc3a = {0.f,0.f,0.f,0.f}, acc3b = {0.f,0.f,0.f,0.f};
        #pragma unroll
        for (int kt = 0; kt < 4; kt += 2) {
            uint4 bu0 = {C2[2*kt].x, C2[2*kt].y, C2[2*kt+1].x, C2[2*kt+1].y};
            uint4 bu1 = {C2[2*kt+2].x, C2[2*kt+2].y, C2[2*kt+3].x, C2[2*kt+3].y};
            acc3a = __builtin_amdgcn_mfma_f32_16x16x32_f16(A3[kt],     __builtin_bit_cast(f16x8, bu0), acc3a, 0, 0, 0);
            acc3b = __builtin_amdgcn_mfma_f32_16x16x32_f16(A3[kt + 1], __builtin_bit_cast(f16x8, bu1), acc3b, 0, 0, 0);
        }

        if (g == 0) {   // rows 0..2 = channels, col = px = li
            float v0 = acc3a[0] + acc3b[0] + b30;
            float v1 = acc3a[1] + acc3b[1] + b31;
            float v2 = acc3a[2] + acc3b[2] + b32;
            if (aff) {
                v0 = fmaf(v0, cw0, cb0);
                v1 = fmaf(v1, cw1, cb1);
                v2 = fmaf(v2, cw2, cb2);
            }
            lr[p0 + li] = v0;
            lr[NPIX_LR + p0 + li] = v1;
            lr[2 * NPIX_LR + p0 + li] = v2;
        }
    }
}

// ---------------- Kernel B: 64 px/wave-iter bilinear + K32-MFMA variance MLP ----------------
#define B_ITERS 2
__global__ __launch_bounds__(256, 4) void inr_upsample_var(
    const float* __restrict__ lr, const int* __restrict__ sidx,
    const float* __restrict__ shv, const float* __restrict__ vb2g,
    const char* __restrict__ ws, float* __restrict__ out)
{
    int tid = threadIdx.x, l = tid & 63, wv = tid >> 6;
    int li = l & 15, g = l >> 4;

    f16x8 A1v[8], A2h[4];
    const uint4* q1 = (const uint4*)(ws + WS_VA1);
    const uint4* qh = (const uint4*)(ws + WS_VA2H);
    #pragma unroll
    for (int t = 0; t < 8; t++) A1v[t] = __builtin_bit_cast(f16x8, q1[t * 64 + l]);
    #pragma unroll
    for (int t = 0; t < 4; t++) A2h[t] = __builtin_bit_cast(f16x8, qh[t * 64 + l]);
    float vb20 = vb2g[0], vb21 = vb2g[1], vb22 = vb2g[2];
    const unsigned ONES = 0x3C003C00u;

    int wbase = (blockIdx.x * 4 + wv) * (64 * B_ITERS);
    #pragma unroll 1
    for (int it = 0; it < B_ITERS; ++it) {
        int pxb = wbase + it * 64;
        int px = pxb + l;
        int b = px >> 18, r = px & 262143;
        int oy = r >> 9, ox = r & 511;

        int my = oy >> 1; int y0, y1; float wy0, wy1;
        if (oy & 1) { y0 = my; y1 = my < 255 ? my + 1 : 255; wy0 = 0.75f; wy1 = 0.25f; }
        else        { y0 = my > 0 ? my - 1 : 0; y1 = my;     wy0 = 0.25f; wy1 = 0.75f; }
        int mx = ox >> 1; int x0, x1; float wx0, wx1;
        if (ox & 1) { x0 = mx; x1 = mx < 255 ? mx + 1 : 255; wx0 = 0.75f; wx1 = 0.25f; }
        else        { x0 = mx > 0 ? mx - 1 : 0; x1 = mx;     wx0 = 0.25f; wx1 = 0.75f; }

        int base = b << 16;
        int i00 = base + y0 * 256 + x0, i01 = base + y0 * 256 + x1;
        int i10 = base + y1 * 256 + x0, i11 = base + y1 * 256 + x1;

        const float* L0 = lr;
        const float* L1 = lr + NPIX_LR;
        const float* L2 = lr + 2 * NPIX_LR;
        float o0 = wy0 * (wx0 * L0[i00] + wx1 * L0[i01]) + wy1 * (wx0 * L0[i10] + wx1 * L0[i11]);
        float o1 = wy0 * (wx0 * L1[i00] + wx1 * L1[i01]) + wy1 * (wx0 * L1[i10] + wx1 * L1[i11]);
        float o2 = wy0 * (wx0 * L2[i00] + wx1 * L2[i01]) + wy1 * (wx0 * L2[i10] + wx1 * L2[i11]);

        {
            float* dst = out + (size_t)px * 3;
            dst[0] = o0; dst[1] = o1; dst[2] = o2;
        }

        #pragma unroll
        for (int j = 0; j < 4; j++) {
            int srcl = j * 16 + li;
            float p0 = __shfl(o0, srcl, 64);
            float p1 = __shfl(o1, srcl, 64);
            float p2 = __shfl(o2, srcl, 64);

            // B1v: g0 k-slots: p0h,p1h,p2h,p0l,p1l,p2l,1,1 ; g1: p0h,p1h,p2h,0... ; g2,g3: 0
            hf2 hp01 = __builtin_amdgcn_cvt_pkrtz(p0, p1);
            hf2 hp2l0 = __builtin_amdgcn_cvt_pkrtz(p2, p0 - (float)hp01[0]);       // (p2h, p0l)
            hf2 hl12 = __builtin_amdgcn_cvt_pkrtz(p1 - (float)hp01[1],
                                                  p2 - (float)hp2l0[0]);           // (p1l, p2l)
            unsigned u01 = __builtin_bit_cast(unsigned, hp01);
            unsigned u20 = __builtin_bit_cast(unsigned, hp2l0);
            unsigned u12 = __builtin_bit_cast(unsigned, hl12);
            uint4 b1u;
            b1u.x = (g <= 1) ? u01 : 0u;
            b1u.y = (g == 0) ? u20 : ((g == 1) ? (u20 & 0xFFFFu) : 0u);
            b1u.z = (g == 0) ? u12 : 0u;
            b1u.w = (g == 0) ? ONES : 0u;
            f16x8 B1 = __builtin_bit_cast(f16x8, b1u);

            // v1: 8 x K32 MFMA (full split in k-slots), relu + hi pack
            uint2 C1[8];
            #pragma unroll
            for (int t = 0; t < 8; t++) {
                f32x4 vh = __builtin_amdgcn_mfma_f32_16x16x32_f16(A1v[t], B1, (f32x4){0.f,0.f,0.f,0.f}, 0, 0, 0);
                C1[t].x = pack_f16pair(fmaxf(vh[0], 0.f), fmaxf(vh[1], 0.f));
                C1[t].y = pack_f16pair(fmaxf(vh[2], 0.f), fmaxf(vh[3], 0.f));
            }

            // v2: 4 x K32 MFMA (sigma-packed A2h)
            f32x4 acc = {0.f, 0.f, 0.f, 0.f};
            #pragma unroll
            for (int kt = 0; kt < 4; kt++) {
                uint4 bu = {C1[2*kt].x, C1[2*kt].y, C1[2*kt+1].x, C1[2*kt+1].y};
                acc = __builtin_amdgcn_mfma_f32_16x16x32_f16(A2h[kt],
                        __builtin_bit_cast(f16x8, bu), acc, 0, 0, 0);
            }

            if (g == 0) {   // rows 0..2 = channels, col = px = li
                float* var = out + OUT_OFF_VAR + (size_t)(pxb + j * 16 + li) * 3;
                var[0] = __expf(acc[0] + vb20);
                var[1] = __expf(acc[1] + vb21);
                var[2] = __expf(acc[2] + vb22);
            }
        }
    }

    if (blockIdx.x == 0 && tid < 16) {
        out[OUT_OFF_DX + tid] = shv[2 * sidx[tid & 7] + (tid >> 3)];
    }
}

extern "C" void kernel_launch(void* const* d_in, const int* in_sizes, int n_in,
                              void* d_out, int out_size, void* d_ws, size_t ws_size,
                              hipStream_t stream)
{
    const float* x    = (const float*)d_in[0];
    const int*   sidx = (const int*)d_in[1];
    const float* shv  = (const float*)d_in[3];
    const float* rot  = (const float*)d_in[4];
    const float* cwp  = (const float*)d_in[5];
    const float* cbp  = (const float*)d_in[6];
    const float* w1   = (const float*)d_in[7];
    const float* b1   = (const float*)d_in[8];
    const float* w2   = (const float*)d_in[9];
    const float* b2   = (const float*)d_in[10];
    const float* w3   = (const float*)d_in[11];
    const float* b3   = (const float*)d_in[12];
    const float* vw1  = (const float*)d_in[13];
    const float* vb1  = (const float*)d_in[14];
    const float* vw2  = (const float*)d_in[15];
    const float* vb2  = (const float*)d_in[16];

    char* ws = (char*)d_ws;
    float* lr = (float*)(ws + WS_LR);

    inr_prep<<<56, 256, 0, stream>>>(w1, b1, w2, w3, vw1, vb1, vw2, ws);
    inr_mlp_mfma<<<512, 256, 0, stream>>>(x, sidx, shv, rot, cwp, cbp, b2, b3, ws, lr);
    inr_upsample_var<<<NPIX_HR / (256 * B_ITERS), 256, 0, stream>>>(lr, sidx, shv, vb2, ws, (float*)d_out);
}

// Round 9
// 75.175 us; speedup vs baseline: 1.5540x; 1.0064x over previous
//
#include <hip/hip_runtime.h>
#include <math.h>

#define HID 128
#define BQ 65536
#define NPIX_LR 524288
#define OW 512
#define NPIX_HR 2097152
#define OUT_OFF_DX 6291456
#define OUT_OFF_VAR 6291472

// ws layout (bytes)
#define WS_A2    0        // 32768 : w2^T K32-frags (32 tiles: T = t2*4+kt), sigma-packed
#define WS_A1    32768    // 8192  : w1^T (+b1) K32-frags (8 m-tiles, split in k-slots)
#define WS_A3    40960    // 4096  : w3^T K32-frags (4 k-tiles), sigma-packed
#define WS_VA1   45056    // 8192  : vw1^T (+vb1) K32-frags (8 m-tiles, hi-only in k0..3)
#define WS_VA2H  53248    // 4096  : vw2^T K32-frags (4 k-tiles), sigma-packed
#define WS_LR    57344    // 6291456 : low-res SoA f32

typedef __fp16   hf2   __attribute__((ext_vector_type(2)));
typedef _Float16 f16x8 __attribute__((ext_vector_type(8)));
typedef float    f32x4 __attribute__((ext_vector_type(4)));

static __device__ inline unsigned pack_f16pair(float a, float b) {
    hf2 h; h[0] = (__fp16)a; h[1] = (__fp16)b;
    return __builtin_bit_cast(unsigned, h);
}
static __device__ inline float f16lo(float v) { return v - (float)(__fp16)v; }

// ---------------- Prep ----------------
// sigma: k-slot for frag elem (kt, g, j) = (2kt + (j>=4))*16 + g*4 + (j&3)
__device__ inline int sigma(int kt, int g, int j) {
    return (2 * kt + (j >> 2)) * 16 + g * 4 + (j & 3);
}

__device__ inline float a1v32(int g, int j, int m, const float* w1, const float* b1) {
    if (g != 0) return 0.f;
    switch (j) {
    case 0: return w1[m];               // w_hi x  (x c_hi)
    case 1: return w1[HID + m];         // w_hi y
    case 2: return w1[m];               // w_hi x  (x c_lo)
    case 3: return w1[HID + m];
    case 4: return f16lo(w1[m]);        // w_lo x  (x c_hi)
    case 5: return f16lo(w1[HID + m]);
    case 6: return b1[m];               // b_hi (x 1)
    case 7: return f16lo(b1[m]);        // b_lo (x 1)
    }
    return 0.f;
}

// single-pass variance layer 1: k-slots g0: vw1r0,vw1r1,vw1r2,vb1; rest 0
__device__ inline float va1v32(int g, int j, int m, const float* vw1, const float* vb1) {
    if (g != 0 || j >= 4) return 0.f;
    if (j < 3) return vw1[j * HID + m];
    return vb1[m];
}

__global__ void inr_prep(const float* __restrict__ w1, const float* __restrict__ b1,
                         const float* __restrict__ w2, const float* __restrict__ w3,
                         const float* __restrict__ vw1, const float* __restrict__ vb1,
                         const float* __restrict__ vw2, char* ws)
{
    int tid = blockIdx.x * 256 + threadIdx.x;
    if (tid < 8192) {                      // A2: 32 tiles (t2*4+kt)
        int d = tid & 3, l = (tid >> 2) & 63, T = tid >> 8;
        int g = l >> 4, li = l & 15, t2 = T >> 2, kt = T & 3;
        int col = 16 * t2 + li;
        int s0 = sigma(kt, g, 2 * d), s1 = sigma(kt, g, 2 * d + 1);
        ((unsigned*)(ws + WS_A2))[tid] = pack_f16pair(w2[s0 * HID + col], w2[s1 * HID + col]);
    } else if (tid < 10240) {              // A1: 8 m-tiles
        int q = tid - 8192;
        int d = q & 3, l = (q >> 2) & 63, t = q >> 8;
        int g = l >> 4, li = l & 15, m = 16 * t + li;
        ((unsigned*)(ws + WS_A1))[q] = pack_f16pair(a1v32(g, 2 * d, m, w1, b1),
                                                    a1v32(g, 2 * d + 1, m, w1, b1));
    } else if (tid < 11264) {              // A3: 4 k-tiles
        int q = tid - 10240;
        int d = q & 3, l = (q >> 2) & 63, kt = q >> 8;
        int g = l >> 4, li = l & 15;
        int s0 = sigma(kt, g, 2 * d), s1 = sigma(kt, g, 2 * d + 1);
        float v0 = (li < 3) ? w3[s0 * 3 + li] : 0.f;
        float v1 = (li < 3) ? w3[s1 * 3 + li] : 0.f;
        ((unsigned*)(ws + WS_A3))[q] = pack_f16pair(v0, v1);
    } else if (tid < 13312) {              // VA1: 8 m-tiles (hi-only)
        int q = tid - 11264;
        int d = q & 3, l = (q >> 2) & 63, t = q >> 8;
        int g = l >> 4, li = l & 15, m = 16 * t + li;
        ((unsigned*)(ws + WS_VA1))[q] = pack_f16pair(va1v32(g, 2 * d, m, vw1, vb1),
                                                     va1v32(g, 2 * d + 1, m, vw1, vb1));
    } else if (tid < 14336) {              // VA2H: 4 k-tiles
        int q = tid - 13312;
        int d = q & 3, l = (q >> 2) & 63, kt = q >> 8;
        int g = l >> 4, li = l & 15;
        int s0 = sigma(kt, g, 2 * d), s1 = sigma(kt, g, 2 * d + 1);
        float v0 = (li < 3) ? vw2[s0 * 3 + li] : 0.f;
        float v1 = (li < 3) ? vw2[s1 * 3 + li] : 0.f;
        ((unsigned*)(ws + WS_VA2H))[q] = pack_f16pair(v0, v1);
    }
}

// ---------------- Kernel A: all-K32-MFMA MLP, one wave owns 16 px x 128 cols ----------------
__global__ __launch_bounds__(256, 2) void inr_mlp_mfma(
    const float* __restrict__ x, const int* __restrict__ sidx,
    const float* __restrict__ shv, const float* __restrict__ rot,
    const float* __restrict__ cw, const float* __restrict__ cb,
    const float* __restrict__ b2g, const float* __restrict__ b3g,
    const char* __restrict__ ws, float* __restrict__ lr)
{
    int tid = threadIdx.x, l = tid & 63, wv = tid >> 6;
    int li = l & 15, g = l >> 4;

    f16x8 A2[32], A1[8], A3[4];
    const uint4* p2 = (const uint4*)(ws + WS_A2);
    #pragma unroll
    for (int i = 0; i < 32; i++) A2[i] = __builtin_bit_cast(f16x8, p2[i * 64 + l]);
    const uint4* p1 = (const uint4*)(ws + WS_A1);
    #pragma unroll
    for (int i = 0; i < 8; i++) A1[i] = __builtin_bit_cast(f16x8, p1[i * 64 + l]);
    const uint4* p3 = (const uint4*)(ws + WS_A3);
    #pragma unroll
    for (int i = 0; i < 4; i++) A3[i] = __builtin_bit_cast(f16x8, p3[i * 64 + l]);

    int base = blockIdx.x * 1024;
    int img = base >> 16;
    int si = sidx[img];
    float ang = rot[si], sn, cs;
    sincosf(ang, &sn, &cs);
    float shx = shv[2*si], shy = shv[2*si+1];
    bool aff = (si != 0);
    float cw0 = cw[si*3+0], cw1 = cw[si*3+1], cw2 = cw[si*3+2];
    float cb0 = cb[si*3+0], cb1 = cb[si*3+1], cb2 = cb[si*3+2];
    float b30 = b3g[0], b31 = b3g[1], b32 = b3g[2];
    const unsigned ONES = 0x3C003C00u;  // (1.0h, 1.0h)

    int pidx = base + wv * 16 + li;
    float2 xv = ((const float2*)x)[pidx];   // prefetch iter 0

    #pragma unroll 1
    for (int it = 0; it < 16; ++it) {
        float2 xvn;
        if (it < 15) xvn = ((const float2*)x)[pidx + (it + 1) * 64];
        int p0 = base + it * 64 + wv * 16;
        float cx = fmaf(cs, xv.x, fmaf(-sn, xv.y, shx));
        float cy = fmaf(sn, xv.x, fmaf(cs, xv.y, shy));
        hf2 ph = __builtin_amdgcn_cvt_pkrtz(cx, cy);
        hf2 pl = __builtin_amdgcn_cvt_pkrtz(cx - (float)ph[0], cy - (float)ph[1]);
        unsigned uh = __builtin_bit_cast(unsigned, ph);
        unsigned ul = __builtin_bit_cast(unsigned, pl);
        // B1 (g0 k-slots): cxh,cyh,cxl,cyl,cxh,cyh,1,1 ; other groups 0
        uint4 b1u;
        b1u.x = (g == 0) ? uh : 0u;
        b1u.y = (g == 0) ? ul : 0u;
        b1u.z = (g == 0) ? uh : 0u;
        b1u.w = (g == 0) ? ONES : 0u;
        f16x8 B1 = __builtin_bit_cast(f16x8, b1u);

        // layer 1: 8 x K32 MFMA -> relu -> pack
        uint2 C1[8];
        #pragma unroll
        for (int t = 0; t < 8; t++) {
            f32x4 h = __builtin_amdgcn_mfma_f32_16x16x32_f16(A1[t], B1, (f32x4){0.f,0.f,0.f,0.f}, 0, 0, 0);
            C1[t].x = pack_f16pair(fmaxf(h[0], 0.f), fmaxf(h[1], 0.f));
            C1[t].y = pack_f16pair(fmaxf(h[2], 0.f), fmaxf(h[3], 0.f));
        }

        // layer 2: 8 m-tiles x 4 k-tiles (sigma-packed A2)
        uint2 C2[8];
        #pragma unroll
        for (int t2 = 0; t2 < 8; t2++) {
            f32x4 c = *(const f32x4*)(b2g + 16 * t2 + g * 4);
            #pragma unroll
            for (int kt = 0; kt < 4; kt++) {
                uint4 bu = {C1[2*kt].x, C1[2*kt].y, C1[2*kt+1].x, C1[2*kt+1].y};
                c = __builtin_amdgcn_mfma_f32_16x16x32_f16(A2[t2 * 4 + kt],
                        __builtin_bit_cast(f16x8, bu), c, 0, 0, 0);
            }
            C2[t2].x = pack_f16pair(fmaxf(c[0], 0.f), fmaxf(c[1], 0.f));
            C2[t2].y = pack_f16pair(fmaxf(c[2], 0.f), fmaxf(c[3], 0.f));
        }

        // layer 3: 4 k-tiles into 2 chains
        f32x4 acc3a = {0.f,0.f,0.f,0.f}, acc3b = {0.f,0.f,0.f,0.f};
        {
            uint4 bu0 = {C2[0].x, C2[0].y, C2[1].x, C2[1].y};
            uint4 bu1 = {C2[2].x, C2[2].y, C2[3].x, C2[3].y};
            uint4 bu2 = {C2[4].x, C2[4].y, C2[5].x, C2[5].y};
            uint4 bu3 = {C2[6].x, C2[6].y, C2[7].x, C2[7].y};
            acc3a = __builtin_amdgcn_mfma_f32_16x16x32_f16(A3[0], __builtin_bit_cast(f16x8, bu0), acc3a, 0, 0, 0);
            acc3b = __builtin_amdgcn_mfma_f32_16x16x32_f16(A3[1], __builtin_bit_cast(f16x8, bu1), acc3b, 0, 0, 0);
            acc3a = __builtin_amdgcn_mfma_f32_16x16x32_f16(A3[2], __builtin_bit_cast(f16x8, bu2), acc3a, 0, 0, 0);
            acc3b = __builtin_amdgcn_mfma_f32_16x16x32_f16(A3[3], __builtin_bit_cast(f16x8, bu3), acc3b, 0, 0, 0);
        }

        if (g == 0) {   // rows 0..2 = channels, col = px = li
            float v0 = acc3a[0] + acc3b[0] + b30;
            float v1 = acc3a[1] + acc3b[1] + b31;
            float v2 = acc3a[2] + acc3b[2] + b32;
            if (aff) {
                v0 = fmaf(v0, cw0, cb0);
                v1 = fmaf(v1, cw1, cb1);
                v2 = fmaf(v2, cw2, cb2);
            }
            lr[p0 + li] = v0;
            lr[NPIX_LR + p0 + li] = v1;
            lr[2 * NPIX_LR + p0 + li] = v2;
        }
        xv = xvn;
    }
}

// ---------------- Kernel B: bilinear (paired taps) + K32-MFMA variance MLP ----------------
#define B_ITERS 4

struct Taps {
    float2 a0, a1, a2;   // row y0: ch0..2, cols (xa, xa+1)
    float2 b0, b1, b2;   // row y1
    float w00, w01, w10, w11;
};

static __device__ inline Taps issue_taps(const float* __restrict__ lr, int px) {
    Taps t;
    int b = px >> 18, r = px & 262143;
    int oy = r >> 9, ox = r & 511;
    int my = oy >> 1, mx = ox >> 1;
    int y0 = (oy & 1) ? my : my - 1;
    int x0 = (ox & 1) ? mx : mx - 1;
    float wy0 = (oy & 1) ? 0.75f : 0.25f;
    float wx0 = (ox & 1) ? 0.75f : 0.25f;
    int y0c = max(y0, 0), y1c = min(y0 + 1, 255);
    int xa = min(max(x0, 0), 254);
    // clamp-emulating weight fixup for the paired x-taps
    float wxa = (x0 < 0) ? 1.f : ((x0 > 254) ? 0.f : wx0);
    float wxb = (x0 < 0) ? 0.f : ((x0 > 254) ? 1.f : 1.f - wx0);
    float wy1 = 1.f - wy0;
    t.w00 = wy0 * wxa; t.w01 = wy0 * wxb;
    t.w10 = wy1 * wxa; t.w11 = wy1 * wxb;
    int base = b << 16;
    int o0 = base + y0c * 256 + xa;
    int o1 = base + y1c * 256 + xa;
    t.a0 = *(const float2*)(lr + o0);
    t.a1 = *(const float2*)(lr + NPIX_LR + o0);
    t.a2 = *(const float2*)(lr + 2 * NPIX_LR + o0);
    t.b0 = *(const float2*)(lr + o1);
    t.b1 = *(const float2*)(lr + NPIX_LR + o1);
    t.b2 = *(const float2*)(lr + 2 * NPIX_LR + o1);
    return t;
}

__global__ __launch_bounds__(256, 4) void inr_upsample_var(
    const float* __restrict__ lr, const int* __restrict__ sidx,
    const float* __restrict__ shv, const float* __restrict__ vb2g,
    const char* __restrict__ ws, float* __restrict__ out)
{
    int tid = threadIdx.x, l = tid & 63, wv = tid >> 6;
    int li = l & 15, g = l >> 4;

    f16x8 A1v[8], A2h[4];
    const uint4* q1 = (const uint4*)(ws + WS_VA1);
    const uint4* qh = (const uint4*)(ws + WS_VA2H);
    #pragma unroll
    for (int t = 0; t < 8; t++) A1v[t] = __builtin_bit_cast(f16x8, q1[t * 64 + l]);
    #pragma unroll
    for (int t = 0; t < 4; t++) A2h[t] = __builtin_bit_cast(f16x8, qh[t * 64 + l]);
    float vb20 = vb2g[0], vb21 = vb2g[1], vb22 = vb2g[2];

    int wbase = (blockIdx.x * 4 + wv) * (64 * B_ITERS);
    Taps tp = issue_taps(lr, wbase + l);   // prefetch iter 0

    #pragma unroll 1
    for (int it = 0; it < B_ITERS; ++it) {
        Taps tn;
        if (it + 1 < B_ITERS) tn = issue_taps(lr, wbase + (it + 1) * 64 + l);
        int pxb = wbase + it * 64;
        int px = pxb + l;

        float o0 = tp.w00 * tp.a0.x + tp.w01 * tp.a0.y + tp.w10 * tp.b0.x + tp.w11 * tp.b0.y;
        float o1 = tp.w00 * tp.a1.x + tp.w01 * tp.a1.y + tp.w10 * tp.b1.x + tp.w11 * tp.b1.y;
        float o2 = tp.w00 * tp.a2.x + tp.w01 * tp.a2.y + tp.w10 * tp.b2.x + tp.w11 * tp.b2.y;

        {
            float* dst = out + (size_t)px * 3;
            dst[0] = o0; dst[1] = o1; dst[2] = o2;
        }

        // pack P to f16 on the OWNING lane (once), shfl the packed dwords
        unsigned u1 = pack_f16pair(o0, o1);
        unsigned u2 = pack_f16pair(o2, 1.0f);

        #pragma unroll
        for (int j = 0; j < 4; j++) {
            int srcl = j * 16 + li;
            unsigned sA = (unsigned)__shfl((int)u1, srcl, 64);
            unsigned sB = (unsigned)__shfl((int)u2, srcl, 64);
            // B1: g0 k-slots 0..3 = (p0h, p1h, p2h, 1.0); everything else 0
            uint4 b1u;
            b1u.x = (g == 0) ? sA : 0u;
            b1u.y = (g == 0) ? sB : 0u;
            b1u.z = 0u;
            b1u.w = 0u;
            f16x8 B1 = __builtin_bit_cast(f16x8, b1u);

            // v1: 8 x K32 MFMA, relu + hi pack
            uint2 C1[8];
            #pragma unroll
            for (int t = 0; t < 8; t++) {
                f32x4 vh = __builtin_amdgcn_mfma_f32_16x16x32_f16(A1v[t], B1, (f32x4){0.f,0.f,0.f,0.f}, 0, 0, 0);
                C1[t].x = pack_f16pair(fmaxf(vh[0], 0.f), fmaxf(vh[1], 0.f));
                C1[t].y = pack_f16pair(fmaxf(vh[2], 0.f), fmaxf(vh[3], 0.f));
            }

            // v2: 4 x K32 MFMA (sigma-packed A2h)
            f32x4 acc = {0.f, 0.f, 0.f, 0.f};
            #pragma unroll
            for (int kt = 0; kt < 4; kt++) {
                uint4 bu = {C1[2*kt].x, C1[2*kt].y, C1[2*kt+1].x, C1[2*kt+1].y};
                acc = __builtin_amdgcn_mfma_f32_16x16x32_f16(A2h[kt],
                        __builtin_bit_cast(f16x8, bu), acc, 0, 0, 0);
            }

            if (g == 0) {   // rows 0..2 = channels, col = px = li
                float* var = out + OUT_OFF_VAR + (size_t)(pxb + j * 16 + li) * 3;
                var[0] = __expf(acc[0] + vb20);
                var[1] = __expf(acc[1] + vb21);
                var[2] = __expf(acc[2] + vb22);
            }
        }
        tp = tn;
    }

    if (blockIdx.x == 0 && tid < 16) {
        out[OUT_OFF_DX + tid] = shv[2 * sidx[tid & 7] + (tid >> 3)];
    }
}

extern "C" void kernel_launch(void* const* d_in, const int* in_sizes, int n_in,
                              void* d_out, int out_size, void* d_ws, size_t ws_size,
                              hipStream_t stream)
{
    const float* x    = (const float*)d_in[0];
    const int*   sidx = (const int*)d_in[1];
    const float* shv  = (const float*)d_in[3];
    const float* rot  = (const float*)d_in[4];
    const float* cwp  = (const float*)d_in[5];
    const float* cbp  = (const float*)d_in[6];
    const float* w1   = (const float*)d_in[7];
    const float* b1   = (const float*)d_in[8];
    const float* w2   = (const float*)d_in[9];
    const float* b2   = (const float*)d_in[10];
    const float* w3   = (const float*)d_in[11];
    const float* b3   = (const float*)d_in[12];
    const float* vw1  = (const float*)d_in[13];
    const float* vb1  = (const float*)d_in[14];
    const float* vw2  = (const float*)d_in[15];
    const float* vb2  = (const float*)d_in[16];

    char* ws = (char*)d_ws;
    float* lr = (float*)(ws + WS_LR);

    inr_prep<<<56, 256, 0, stream>>>(w1, b1, w2, w3, vw1, vb1, vw2, ws);
    inr_mlp_mfma<<<512, 256, 0, stream>>>(x, sidx, shv, rot, cwp, cbp, b2, b3, ws, lr);
    inr_upsample_var<<<NPIX_HR / (256 * B_ITERS), 256, 0, stream>>>(lr, sidx, shv, vb2, ws, (float*)d_out);
}